// Round 6
// baseline (275.363 us; speedup 1.0000x reference)
//
#include <hip/hip_runtime.h>
#include <cstdint>

#define TOKENS 16384
#define DMODEL 512
#define DIM    1024
#define NQ     10
#define NL     2
#define BM     128
#define BN     128
#define BK     32

typedef __bf16 bf16x8 __attribute__((ext_vector_type(8)));
typedef float  f32x4  __attribute__((ext_vector_type(4)));
typedef unsigned short u16x8 __attribute__((ext_vector_type(8)));

__device__ __forceinline__ float b2f(unsigned short h) {
    union { unsigned u; float f; } v; v.u = ((unsigned)h) << 16; return v.f;
}
__device__ __forceinline__ unsigned short f2b(float f) {
    unsigned u = __builtin_bit_cast(unsigned, f);
    return (unsigned short)((u + 0x7FFFu + ((u >> 16) & 1u)) >> 16);  // RNE
}
__device__ __forceinline__ float2 cmul(float2 a, float2 b) {
    return make_float2(a.x * b.x - a.y * b.y, a.x * b.y + a.y * b.x);
}
__device__ __forceinline__ float2 cadd(float2 a, float2 b) {
    return make_float2(a.x + b.x, a.y + b.y);
}
__device__ __forceinline__ void async_copy16(const void* g, void* l) {
    __builtin_amdgcn_global_load_lds((const __attribute__((address_space(1))) void*)g,
                                     (__attribute__((address_space(3))) void*)l, 16, 0, 0);
}

// ---------------------------------------------------------------------------
// misc: blocks 0..511 transpose W_in fp32->bf16 into wtT[512][1024];
//       blocks 512..2559 grid-stride convert x and W_out to bf16.
// ---------------------------------------------------------------------------
__global__ __launch_bounds__(256)
void misc_kernel(const float* __restrict__ x,  unsigned short* __restrict__ xb,
                 const float* __restrict__ w2, unsigned short* __restrict__ w2b,
                 const float* __restrict__ W_in, unsigned short* __restrict__ wtT) {
    const int bid = blockIdx.x;
    if (bid < 512) {
        __shared__ float tile[32][33];
        const int tx = threadIdx.x & 31, ty = threadIdx.x >> 5;   // 32x8
        const int d0 = (bid & 15) * 32, j0 = (bid >> 4) * 32;
        #pragma unroll
        for (int i = 0; i < 32; i += 8)
            tile[ty + i][tx] = W_in[(size_t)(j0 + ty + i) * DMODEL + d0 + tx];
        __syncthreads();
        #pragma unroll
        for (int i = 0; i < 32; i += 8)
            wtT[(size_t)(d0 + ty + i) * DIM + j0 + tx] = f2b(tile[tx][ty + i]);
        return;
    }
    const int NX4 = TOKENS * DMODEL / 4;
    const int NW4 = DMODEL * DIM / 4;
    const int total = NX4 + NW4;
    const int stride = 2048 * 256;
    for (int i = (bid - 512) * 256 + threadIdx.x; i < total; i += stride) {
        const float* s; unsigned short* d; int j;
        if (i < NX4) { s = x;  d = xb;  j = i; }
        else         { s = w2; d = w2b; j = i - NX4; }
        float4 v = *(const float4*)&s[(size_t)j * 4];
        ushort4 o;
        o.x = f2b(v.x); o.y = f2b(v.y); o.z = f2b(v.z); o.w = f2b(v.w);
        *(ushort4*)&d[(size_t)j * 4] = o;
    }
}

// ---------------------------------------------------------------------------
// buildU: prep inlined. Each block fuses the 20 gates into LDS, then one wave
// per row c applies the TRANSPOSED circuit to basis e_c. Rows interleaved:
// row 2c = Re U[c,:], row 2c+1 = Im U[c,:].
// ---------------------------------------------------------------------------
__global__ __launch_bounds__(256)
void buildU_kernel(const float* __restrict__ rot, const float* __restrict__ ent,
                   unsigned short* __restrict__ U) {
    __shared__ float2 Gs[NL * NQ * 4];
    const int t = threadIdx.x, lane = t & 63;
    const int c = blockIdx.x * 4 + (t >> 6);

    if (t < NL * NQ) {
        float tx = rot[t * 3 + 0] * 0.5f;
        float ty = rot[t * 3 + 1] * 0.5f;
        float tz = rot[t * 3 + 2] * 0.5f;
        float cx = cosf(tx), sx = sinf(tx);
        float cy = cosf(ty), sy = sinf(ty);
        float cz = cosf(tz), sz = sinf(tz);
        float2 rx00 = make_float2(cx, 0.f),  rx01 = make_float2(0.f, -sx);
        float2 rx10 = make_float2(0.f, -sx), rx11 = make_float2(cx, 0.f);
        float2 ry00 = make_float2(cy, 0.f),  ry01 = make_float2(-sy, 0.f);
        float2 ry10 = make_float2(sy, 0.f),  ry11 = make_float2(cy, 0.f);
        float2 m00 = cadd(cmul(ry00, rx00), cmul(ry01, rx10));
        float2 m01 = cadd(cmul(ry00, rx01), cmul(ry01, rx11));
        float2 m10 = cadd(cmul(ry10, rx00), cmul(ry11, rx10));
        float2 m11 = cadd(cmul(ry10, rx01), cmul(ry11, rx11));
        float2 e0 = make_float2(cz, -sz), e1 = make_float2(cz, sz);
        Gs[t * 4 + 0] = cmul(e0, m00);
        Gs[t * 4 + 1] = cmul(e0, m01);
        Gs[t * 4 + 2] = cmul(e1, m10);
        Gs[t * 4 + 3] = cmul(e1, m11);
    }
    float ef[NL * (NQ - 1)];
    #pragma unroll
    for (int i = 0; i < NL * (NQ - 1); i++) ef[i] = ent[i];
    __syncthreads();

    float2 amp[16];
    #pragma unroll
    for (int r = 0; r < 16; r++)
        amp[r] = make_float2((lane * 16 + r == c) ? 1.f : 0.f, 0.f);

    #pragma unroll 1
    for (int li = 0; li < NL; li++) {
        const int l = NL - 1 - li;
        // CZ diagonal first (transposed circuit): amp for index lane*16+r
        #pragma unroll
        for (int r = 0; r < 16; r++) {
            int idx = lane * 16 + r;
            float ang = 0.f;
            #pragma unroll
            for (int q = 0; q < NQ - 1; q++) {
                int both = ((idx >> (9 - q)) & 1) & ((idx >> (8 - q)) & 1);
                if (both) ang += ef[l * (NQ - 1) + q];
            }
            amp[r] = cmul(amp[r], make_float2(cosf(ang), sinf(ang)));
        }
        const float2* Gl = Gs + l * NQ * 4;
        #pragma unroll
        for (int qq = 0; qq < NQ; qq++) {
            const int q = 9 - qq;
            float2 u00 = Gl[q * 4 + 0], u10 = Gl[q * 4 + 1];   // transposed:
            float2 u01 = Gl[q * 4 + 2], u11 = Gl[q * 4 + 3];   // u01<->u10
            if (q >= 6) {
                const int S = 1 << (9 - q);
                #pragma unroll
                for (int r = 0; r < 16; r++) {
                    if (r & S) continue;
                    float2 a = amp[r], b = amp[r + S];
                    float2 n0, n1;
                    n0.x = u00.x * a.x - u00.y * a.y + u01.x * b.x - u01.y * b.y;
                    n0.y = u00.x * a.y + u00.y * a.x + u01.x * b.y + u01.y * b.x;
                    n1.x = u10.x * a.x - u10.y * a.y + u11.x * b.x - u11.y * b.y;
                    n1.y = u10.x * a.y + u10.y * a.x + u11.x * b.y + u11.y * b.x;
                    amp[r] = n0; amp[r + S] = n1;
                }
            } else {
                const int mask = 32 >> q;
                int bit = (lane >> (5 - q)) & 1;
                float2 ua = bit ? u11 : u00;
                float2 ub = bit ? u10 : u01;
                #pragma unroll
                for (int r = 0; r < 16; r++) {
                    float px = __shfl_xor(amp[r].x, mask, 64);
                    float py = __shfl_xor(amp[r].y, mask, 64);
                    float nx = ua.x * amp[r].x - ua.y * amp[r].y + ub.x * px - ub.y * py;
                    float ny = ua.x * amp[r].y + ua.y * amp[r].x + ub.x * py + ub.y * px;
                    amp[r] = make_float2(nx, ny);
                }
            }
        }
    }

    u16x8 o0, o1, p0, p1;
    #pragma unroll
    for (int r = 0; r < 8; r++) {
        o0[r] = f2b(amp[r].x);     o1[r] = f2b(amp[r + 8].x);
        p0[r] = f2b(amp[r].y);     p1[r] = f2b(amp[r + 8].y);
    }
    unsigned short* rowRe = U + (size_t)(2 * c) * DIM + lane * 16;
    unsigned short* rowIm = U + (size_t)(2 * c + 1) * DIM + lane * 16;
    *(u16x8*)rowRe = o0; *(u16x8*)(rowRe + 8) = o1;
    *(u16x8*)rowIm = p0; *(u16x8*)(rowIm + 8) = p1;
}

// ---------------------------------------------------------------------------
// fold: blockIdx.y<16 -> W1c[j,d] = sum_k Ucat[j,k]*wtT[d,k] (bf16 GEMM)
//       blockIdx.y==16 -> b2[j] = sum_k Ucat[j,k]*b_in[k]
// ---------------------------------------------------------------------------
__global__ __launch_bounds__(256)
void fold_kernel(const unsigned short* __restrict__ A, const unsigned short* __restrict__ B,
                 const float* __restrict__ bin, unsigned short* __restrict__ C,
                 float* __restrict__ b2) {
    const int t = threadIdx.x;
    const int wave = t >> 6, lane = t & 63;
    if (blockIdx.y == 16) {
        const int jbase = (blockIdx.x * 4 + wave) * 128;
        for (int it = 0; it < 128; it++) {
            const unsigned short* row = A + (size_t)(jbase + it) * DIM;
            float acc = 0.f;
            #pragma unroll
            for (int i = 0; i < 16; i++) {
                int k = lane + i * 64;
                acc += b2f(row[k]) * bin[k];
            }
            #pragma unroll
            for (int m = 1; m < 64; m <<= 1) acc += __shfl_xor(acc, m, 64);
            if (lane == 0) b2[jbase + it] = acc;
        }
        return;
    }
    __shared__ unsigned short lds_a[BM * BK];
    __shared__ unsigned short lds_b[BN * BK];
    const int wm = wave >> 1, wn = wave & 1;
    const int bm0 = blockIdx.y * BM;
    const int bn0 = blockIdx.x * BN;
    const int K = DIM, N = DMODEL;

    f32x4 acc[4][4] = {};
    const int c0 = t, c1 = t + 256;
    const int r0 = c0 >> 2, g0 = (c0 & 3) ^ ((r0 >> 1) & 3);
    const int r1 = c1 >> 2, g1 = (c1 & 3) ^ ((r1 >> 1) & 3);

    for (int k0 = 0; k0 < K; k0 += BK) {
        async_copy16(A + (size_t)(bm0 + r0) * K + k0 + g0 * 8, (char*)lds_a + wave * 1024);
        async_copy16(A + (size_t)(bm0 + r1) * K + k0 + g1 * 8, (char*)lds_a + wave * 1024 + 4096);
        async_copy16(B + (size_t)(bn0 + r0) * K + k0 + g0 * 8, (char*)lds_b + wave * 1024);
        async_copy16(B + (size_t)(bn0 + r1) * K + k0 + g1 * 8, (char*)lds_b + wave * 1024 + 4096);
        __syncthreads();

        bf16x8 af[4], bfr[4];
        #pragma unroll
        for (int i = 0; i < 4; i++) {
            int row = wm * 64 + i * 16 + (lane & 15);
            int slot = (lane >> 4) ^ ((row >> 1) & 3);
            af[i] = *(const bf16x8*)&lds_a[row * BK + slot * 8];
            int nrow = wn * 64 + i * 16 + (lane & 15);
            int nslot = (lane >> 4) ^ ((nrow >> 1) & 3);
            bfr[i] = *(const bf16x8*)&lds_b[nrow * BK + nslot * 8];
        }
        #pragma unroll
        for (int i = 0; i < 4; i++)
            #pragma unroll
            for (int j = 0; j < 4; j++)
                acc[i][j] = __builtin_amdgcn_mfma_f32_16x16x32_bf16(af[i], bfr[j], acc[i][j], 0, 0, 0);
        __syncthreads();
    }

    #pragma unroll
    for (int i = 0; i < 4; i++)
        #pragma unroll
        for (int j = 0; j < 4; j++) {
            int col = bn0 + wn * 64 + j * 16 + (lane & 15);
            #pragma unroll
            for (int r = 0; r < 4; r++) {
                int row = bm0 + wm * 64 + i * 16 + (lane >> 4) * 4 + r;
                C[(size_t)row * N + col] = f2b(acc[i][j][r]);
            }
        }
}

// ---------------------------------------------------------------------------
// gemm1: y = x_bf @ W1c^T + b2 (re/im interleaved cols). Epilogue: square,
// pair-sum, write p bf16 [TOKENS][DIM]. No atomics. Grid: x=M (fast), y=N.
// ---------------------------------------------------------------------------
__global__ __launch_bounds__(256)
void gemm1_kernel(const unsigned short* __restrict__ A, const unsigned short* __restrict__ B,
                  const float* __restrict__ bias, unsigned short* __restrict__ P) {
    const int K = DMODEL;
    __shared__ unsigned short lds_a[BM * BK];
    __shared__ unsigned short lds_b[BN * BK];
    const int t = threadIdx.x;
    const int wave = t >> 6, lane = t & 63;
    const int wm = wave >> 1, wn = wave & 1;
    const int bm0 = blockIdx.x * BM;    // M fast-varying: co-resident blocks
    const int bn0 = blockIdx.y * BN;    // share the B strip

    f32x4 acc[4][4] = {};
    const int c0 = t, c1 = t + 256;
    const int r0 = c0 >> 2, g0 = (c0 & 3) ^ ((r0 >> 1) & 3);
    const int r1 = c1 >> 2, g1 = (c1 & 3) ^ ((r1 >> 1) & 3);

    for (int k0 = 0; k0 < K; k0 += BK) {
        async_copy16(A + (size_t)(bm0 + r0) * K + k0 + g0 * 8, (char*)lds_a + wave * 1024);
        async_copy16(A + (size_t)(bm0 + r1) * K + k0 + g1 * 8, (char*)lds_a + wave * 1024 + 4096);
        async_copy16(B + (size_t)(bn0 + r0) * K + k0 + g0 * 8, (char*)lds_b + wave * 1024);
        async_copy16(B + (size_t)(bn0 + r1) * K + k0 + g1 * 8, (char*)lds_b + wave * 1024 + 4096);
        __syncthreads();

        bf16x8 af[4], bfr[4];
        #pragma unroll
        for (int i = 0; i < 4; i++) {
            int row = wm * 64 + i * 16 + (lane & 15);
            int slot = (lane >> 4) ^ ((row >> 1) & 3);
            af[i] = *(const bf16x8*)&lds_a[row * BK + slot * 8];
            int nrow = wn * 64 + i * 16 + (lane & 15);
            int nslot = (lane >> 4) ^ ((nrow >> 1) & 3);
            bfr[i] = *(const bf16x8*)&lds_b[nrow * BK + nslot * 8];
        }
        #pragma unroll
        for (int i = 0; i < 4; i++)
            #pragma unroll
            for (int j = 0; j < 4; j++)
                acc[i][j] = __builtin_amdgcn_mfma_f32_16x16x32_bf16(af[i], bfr[j], acc[i][j], 0, 0, 0);
        __syncthreads();
    }

    // epilogue: p = re^2 + im^2 (re/im in adjacent lanes), even lanes store
    #pragma unroll
    for (int i = 0; i < 4; i++) {
        #pragma unroll
        for (int j = 0; j < 4; j++) {
            int col = bn0 + wn * 64 + j * 16 + (lane & 15);
            float bv = bias[col];
            #pragma unroll
            for (int r = 0; r < 4; r++) {
                int row = bm0 + wm * 64 + i * 16 + (lane >> 4) * 4 + r;
                float val = acc[i][j][r] + bv;
                float v2 = val * val;
                float v2p = v2 + __shfl_xor(v2, 1, 64);
                if (!(lane & 1))
                    P[(size_t)row * DIM + (col >> 1)] = f2b(v2p);
            }
        }
    }
}

// ---------------------------------------------------------------------------
// gemm2_ln: out = LN( (p@W_out^T)/n2 + b_out ) * ln_w + ln_b, where
// n2[row] = sum_k p[row,k] computed IN-KERNEL via all-ones B-fragment MFMA
// (wave 0 only). BM=32 x BN=512 (full d_model per block).
// ---------------------------------------------------------------------------
__global__ __launch_bounds__(256)
void gemm2_ln_kernel(const unsigned short* __restrict__ A,   // p [TOKENS][DIM]
                     const unsigned short* __restrict__ B,   // w2b [DMODEL][DIM]
                     const float* __restrict__ bias,
                     const float* __restrict__ lw, const float* __restrict__ lb,
                     float* __restrict__ out) {
    __shared__ unsigned short lds_a[32 * BK];      // 2 KB
    __shared__ unsigned short lds_b[512 * BK];     // 32 KB
    __shared__ float redS[4][32], redQ[4][32];
    __shared__ float muS[32], rsS[32], n2s[32];
    const int t = threadIdx.x, wave = t >> 6, lane = t & 63;
    const int bm0 = blockIdx.x * 32;

    f32x4 acc[2][8] = {};
    f32x4 accN[2] = {};
    bf16x8 ones;
    #pragma unroll
    for (int r = 0; r < 8; r++) ones[r] = (__bf16)1.0f;

    const int ra = t >> 2, ga = (t & 3) ^ ((ra >> 1) & 3);   // A chunks (t<128)

    for (int k0 = 0; k0 < DIM; k0 += BK) {
        if (wave < 2)
            async_copy16(A + (size_t)(bm0 + ra) * DIM + k0 + ga * 8,
                         (char*)lds_a + wave * 1024);
        #pragma unroll
        for (int s = 0; s < 8; s++) {
            int c = t + s * 256;
            int r = c >> 2, g = (c & 3) ^ ((r >> 1) & 3);
            async_copy16(B + (size_t)r * DIM + k0 + g * 8,
                         (char*)lds_b + s * 4096 + wave * 1024);
        }
        __syncthreads();

        bf16x8 af[2], bfr[8];
        #pragma unroll
        for (int i = 0; i < 2; i++) {
            int row = i * 16 + (lane & 15);
            int slot = (lane >> 4) ^ ((row >> 1) & 3);
            af[i] = *(const bf16x8*)&lds_a[row * BK + slot * 8];
        }
        #pragma unroll
        for (int j = 0; j < 8; j++) {
            int nrow = wave * 128 + j * 16 + (lane & 15);
            int nslot = (lane >> 4) ^ ((nrow >> 1) & 3);
            bfr[j] = *(const bf16x8*)&lds_b[nrow * BK + nslot * 8];
        }
        #pragma unroll
        for (int i = 0; i < 2; i++)
            #pragma unroll
            for (int j = 0; j < 8; j++)
                acc[i][j] = __builtin_amdgcn_mfma_f32_16x16x32_bf16(af[i], bfr[j], acc[i][j], 0, 0, 0);
        if (wave == 0) {
            #pragma unroll
            for (int i = 0; i < 2; i++)
                accN[i] = __builtin_amdgcn_mfma_f32_16x16x32_bf16(af[i], ones, accN[i], 0, 0, 0);
        }
        __syncthreads();
    }

    // n2 rowsums -> LDS
    if (wave == 0 && (lane & 15) == 0) {
        #pragma unroll
        for (int i = 0; i < 2; i++)
            #pragma unroll
            for (int r = 0; r < 4; r++)
                n2s[i * 16 + (lane >> 4) * 4 + r] = accN[i][r];
    }
    __syncthreads();

    // ---- epilogue: scale by 1/n2, +bias, LN over the 512-wide row ----
    const int colb = wave * 128;
    float nn[8];
    #pragma unroll
    for (int i = 0; i < 2; i++)
        #pragma unroll
        for (int r = 0; r < 4; r++) {
            int rl = i * 16 + (lane >> 4) * 4 + r;
            nn[i * 4 + r] = 1.0f / fmaxf(n2s[rl], 1e-24f);
        }
    float pS[8], pQ[8];
    #pragma unroll
    for (int i = 0; i < 2; i++)
        #pragma unroll
        for (int r = 0; r < 4; r++) {
            float s = 0.f, q = 0.f;
            #pragma unroll
            for (int j = 0; j < 8; j++) {
                int col = colb + j * 16 + (lane & 15);
                float val = acc[i][j][r] * nn[i * 4 + r] + bias[col];
                acc[i][j][r] = val;
                s += val; q += val * val;
            }
            s += __shfl_xor(s, 1, 64); q += __shfl_xor(q, 1, 64);
            s += __shfl_xor(s, 2, 64); q += __shfl_xor(q, 2, 64);
            s += __shfl_xor(s, 4, 64); q += __shfl_xor(q, 4, 64);
            s += __shfl_xor(s, 8, 64); q += __shfl_xor(q, 8, 64);
            pS[i * 4 + r] = s; pQ[i * 4 + r] = q;
        }
    if ((lane & 15) == 0) {
        #pragma unroll
        for (int i = 0; i < 2; i++)
            #pragma unroll
            for (int r = 0; r < 4; r++) {
                int rl = i * 16 + (lane >> 4) * 4 + r;
                redS[wave][rl] = pS[i * 4 + r];
                redQ[wave][rl] = pQ[i * 4 + r];
            }
    }
    __syncthreads();
    if (t < 32) {
        float s = redS[0][t] + redS[1][t] + redS[2][t] + redS[3][t];
        float q = redQ[0][t] + redQ[1][t] + redQ[2][t] + redQ[3][t];
        float mu = s * (1.0f / DMODEL);
        float var = q * (1.0f / DMODEL) - mu * mu;
        muS[t] = mu;
        rsS[t] = rsqrtf(var + 1e-5f);
    }
    __syncthreads();
    #pragma unroll
    for (int i = 0; i < 2; i++)
        #pragma unroll
        for (int j = 0; j < 8; j++) {
            int col = colb + j * 16 + (lane & 15);
            float w = lw[col], bb = lb[col];
            #pragma unroll
            for (int r = 0; r < 4; r++) {
                int rl = i * 16 + (lane >> 4) * 4 + r;
                out[(size_t)(bm0 + rl) * DMODEL + col] =
                    (acc[i][j][r] - muS[rl]) * rsS[rl] * w + bb;
            }
        }
}

extern "C" void kernel_launch(void* const* d_in, const int* in_sizes, int n_in,
                              void* d_out, int out_size, void* d_ws, size_t ws_size,
                              hipStream_t stream) {
    (void)in_sizes; (void)n_in; (void)out_size; (void)ws_size;
    const float* x     = (const float*)d_in[0];
    const float* W_in  = (const float*)d_in[1];
    const float* b_in  = (const float*)d_in[2];
    const float* W_out = (const float*)d_in[3];
    const float* b_out = (const float*)d_in[4];
    const float* rot   = (const float*)d_in[5];
    const float* ent   = (const float*)d_in[6];
    const float* ln_w  = (const float*)d_in[7];
    const float* ln_b  = (const float*)d_in[8];
    float* out = (float*)d_out;

    char* ws = (char*)d_ws;
    unsigned short* p    = (unsigned short*)ws;                     // [16384][1024] 32 MB
    unsigned short* x_bf = (unsigned short*)(ws + 33554432ull);     // 16 MB
    unsigned short* wtT  = (unsigned short*)(ws + 50331648ull);     // [512][1024] 1 MB
    unsigned short* w2b  = (unsigned short*)(ws + 51380224ull);     // [512][1024] 1 MB
    unsigned short* Ucat = (unsigned short*)(ws + 52428800ull);     // [2048][1024] 4 MB
    unsigned short* W1c  = (unsigned short*)(ws + 56623104ull);     // [2048][512] 2 MB
    float*          b2   = (float*)(ws + 58720256ull);              // [2048] 8 KB
    // high-water ~56 MB

    misc_kernel<<<2560, 256, 0, stream>>>(x, x_bf, W_out, w2b, W_in, wtT);
    buildU_kernel<<<DIM / 4, 256, 0, stream>>>(rot, ent, Ucat);
    fold_kernel<<<dim3(DMODEL / BN, 17), 256, 0, stream>>>(Ucat, wtT, b_in, W1c, b2);
    gemm1_kernel<<<dim3(TOKENS / BM, 2 * DIM / BN), 256, 0, stream>>>(
        x_bf, W1c, b2, p);
    gemm2_ln_kernel<<<TOKENS / 32, 256, 0, stream>>>(
        p, w2b, b_out, ln_w, ln_b, out);
}

// Round 7
// 214.883 us; speedup vs baseline: 1.2815x; 1.2815x over previous
//
#include <hip/hip_runtime.h>
#include <cstdint>

#define TOKENS 16384
#define DMODEL 512
#define DIM    1024
#define NQ     10
#define NL     2
#define BM     128
#define BN     128
#define BK     32

typedef __bf16 bf16x8 __attribute__((ext_vector_type(8)));
typedef float  f32x4  __attribute__((ext_vector_type(4)));
typedef unsigned short u16x8 __attribute__((ext_vector_type(8)));

__device__ __forceinline__ float b2f(unsigned short h) {
    union { unsigned u; float f; } v; v.u = ((unsigned)h) << 16; return v.f;
}
__device__ __forceinline__ unsigned short f2b(float f) {
    unsigned u = __builtin_bit_cast(unsigned, f);
    return (unsigned short)((u + 0x7FFFu + ((u >> 16) & 1u)) >> 16);  // RNE
}
__device__ __forceinline__ float2 cmul(float2 a, float2 b) {
    return make_float2(a.x * b.x - a.y * b.y, a.x * b.y + a.y * b.x);
}
__device__ __forceinline__ float2 cadd(float2 a, float2 b) {
    return make_float2(a.x + b.x, a.y + b.y);
}
__device__ __forceinline__ void async_copy16(const void* g, void* l) {
    __builtin_amdgcn_global_load_lds((const __attribute__((address_space(1))) void*)g,
                                     (__attribute__((address_space(3))) void*)l, 16, 0, 0);
}

// ---------------------------------------------------------------------------
// prep_all: block-id branched fused prep.
//   blocks 0..255    : buildU (4 U-rows per block, 1 per wave) + b2 fold
//   blocks 256..767  : W_in fp32 -> wtT[512][1024] bf16 transposed
//   blocks 768..2815 : grid-stride fp32->bf16 conv of x and W_out
// ---------------------------------------------------------------------------
__global__ __launch_bounds__(256)
void prep_all_kernel(const float* __restrict__ x,  unsigned short* __restrict__ xb,
                     const float* __restrict__ w2, unsigned short* __restrict__ w2b,
                     const float* __restrict__ W_in, unsigned short* __restrict__ wtT,
                     const float* __restrict__ rot, const float* __restrict__ ent,
                     const float* __restrict__ bin,
                     unsigned short* __restrict__ U, float* __restrict__ b2) {
    const int bid = blockIdx.x;
    const int t = threadIdx.x;

    if (bid < 256) {
        // ---------------- buildU + b2 ----------------
        __shared__ float2 Gs[NL * NQ * 4];
        const int lane = t & 63;
        const int c = bid * 4 + (t >> 6);

        if (t < NL * NQ) {
            float tx = rot[t * 3 + 0] * 0.5f;
            float ty = rot[t * 3 + 1] * 0.5f;
            float tz = rot[t * 3 + 2] * 0.5f;
            float cx = cosf(tx), sx = sinf(tx);
            float cy = cosf(ty), sy = sinf(ty);
            float cz = cosf(tz), sz = sinf(tz);
            float2 rx00 = make_float2(cx, 0.f),  rx01 = make_float2(0.f, -sx);
            float2 rx10 = make_float2(0.f, -sx), rx11 = make_float2(cx, 0.f);
            float2 ry00 = make_float2(cy, 0.f),  ry01 = make_float2(-sy, 0.f);
            float2 ry10 = make_float2(sy, 0.f),  ry11 = make_float2(cy, 0.f);
            float2 m00 = cadd(cmul(ry00, rx00), cmul(ry01, rx10));
            float2 m01 = cadd(cmul(ry00, rx01), cmul(ry01, rx11));
            float2 m10 = cadd(cmul(ry10, rx00), cmul(ry11, rx10));
            float2 m11 = cadd(cmul(ry10, rx01), cmul(ry11, rx11));
            float2 e0 = make_float2(cz, -sz), e1 = make_float2(cz, sz);
            Gs[t * 4 + 0] = cmul(e0, m00);
            Gs[t * 4 + 1] = cmul(e0, m01);
            Gs[t * 4 + 2] = cmul(e1, m10);
            Gs[t * 4 + 3] = cmul(e1, m11);
        }
        float ef[NL * (NQ - 1)];
        #pragma unroll
        for (int i = 0; i < NL * (NQ - 1); i++) ef[i] = ent[i];
        __syncthreads();

        float2 amp[16];
        #pragma unroll
        for (int r = 0; r < 16; r++)
            amp[r] = make_float2((lane * 16 + r == c) ? 1.f : 0.f, 0.f);

        #pragma unroll 1
        for (int li = 0; li < NL; li++) {
            const int l = NL - 1 - li;
            #pragma unroll
            for (int r = 0; r < 16; r++) {
                int idx = lane * 16 + r;
                float ang = 0.f;
                #pragma unroll
                for (int q = 0; q < NQ - 1; q++) {
                    int both = ((idx >> (9 - q)) & 1) & ((idx >> (8 - q)) & 1);
                    if (both) ang += ef[l * (NQ - 1) + q];
                }
                amp[r] = cmul(amp[r], make_float2(cosf(ang), sinf(ang)));
            }
            const float2* Gl = Gs + l * NQ * 4;
            #pragma unroll
            for (int qq = 0; qq < NQ; qq++) {
                const int q = 9 - qq;
                float2 u00 = Gl[q * 4 + 0], u10 = Gl[q * 4 + 1];   // transposed:
                float2 u01 = Gl[q * 4 + 2], u11 = Gl[q * 4 + 3];   // u01<->u10
                if (q >= 6) {
                    const int S = 1 << (9 - q);
                    #pragma unroll
                    for (int r = 0; r < 16; r++) {
                        if (r & S) continue;
                        float2 a = amp[r], b = amp[r + S];
                        float2 n0, n1;
                        n0.x = u00.x * a.x - u00.y * a.y + u01.x * b.x - u01.y * b.y;
                        n0.y = u00.x * a.y + u00.y * a.x + u01.x * b.y + u01.y * b.x;
                        n1.x = u10.x * a.x - u10.y * a.y + u11.x * b.x - u11.y * b.y;
                        n1.y = u10.x * a.y + u10.y * a.x + u11.x * b.y + u11.y * b.x;
                        amp[r] = n0; amp[r + S] = n1;
                    }
                } else {
                    const int mask = 32 >> q;
                    int bit = (lane >> (5 - q)) & 1;
                    float2 ua = bit ? u11 : u00;
                    float2 ub = bit ? u10 : u01;
                    #pragma unroll
                    for (int r = 0; r < 16; r++) {
                        float px = __shfl_xor(amp[r].x, mask, 64);
                        float py = __shfl_xor(amp[r].y, mask, 64);
                        float nx = ua.x * amp[r].x - ua.y * amp[r].y + ub.x * px - ub.y * py;
                        float ny = ua.x * amp[r].y + ua.y * amp[r].x + ub.x * py + ub.y * px;
                        amp[r] = make_float2(nx, ny);
                    }
                }
            }
        }

        // b2 fold at full fp32 precision: b2[2c]=Re(U@bin), b2[2c+1]=Im
        float accRe = 0.f, accIm = 0.f;
        #pragma unroll
        for (int i = 0; i < 4; i++) {
            float4 bv = *(const float4*)&bin[lane * 16 + i * 4];
            accRe += amp[i * 4 + 0].x * bv.x + amp[i * 4 + 1].x * bv.y
                   + amp[i * 4 + 2].x * bv.z + amp[i * 4 + 3].x * bv.w;
            accIm += amp[i * 4 + 0].y * bv.x + amp[i * 4 + 1].y * bv.y
                   + amp[i * 4 + 2].y * bv.z + amp[i * 4 + 3].y * bv.w;
        }
        #pragma unroll
        for (int m = 1; m < 64; m <<= 1) {
            accRe += __shfl_xor(accRe, m, 64);
            accIm += __shfl_xor(accIm, m, 64);
        }
        if (lane == 0) { b2[2 * c] = accRe; b2[2 * c + 1] = accIm; }

        u16x8 o0, o1, p0, p1;
        #pragma unroll
        for (int r = 0; r < 8; r++) {
            o0[r] = f2b(amp[r].x);     o1[r] = f2b(amp[r + 8].x);
            p0[r] = f2b(amp[r].y);     p1[r] = f2b(amp[r + 8].y);
        }
        unsigned short* rowRe = U + (size_t)(2 * c) * DIM + lane * 16;
        unsigned short* rowIm = U + (size_t)(2 * c + 1) * DIM + lane * 16;
        *(u16x8*)rowRe = o0; *(u16x8*)(rowRe + 8) = o1;
        *(u16x8*)rowIm = p0; *(u16x8*)(rowIm + 8) = p1;
        return;
    }

    if (bid < 768) {
        // ---------------- W_in transpose -> wtT ----------------
        __shared__ float tile[32][33];
        const int b2i = bid - 256;
        const int tx = t & 31, ty = t >> 5;   // 32x8
        const int d0 = (b2i & 15) * 32, j0 = (b2i >> 4) * 32;
        #pragma unroll
        for (int i = 0; i < 32; i += 8)
            tile[ty + i][tx] = W_in[(size_t)(j0 + ty + i) * DMODEL + d0 + tx];
        __syncthreads();
        #pragma unroll
        for (int i = 0; i < 32; i += 8)
            wtT[(size_t)(d0 + ty + i) * DIM + j0 + tx] = f2b(tile[tx][ty + i]);
        return;
    }

    // ---------------- x / W_out fp32 -> bf16 ----------------
    const int NX4 = TOKENS * DMODEL / 4;
    const int NW4 = DMODEL * DIM / 4;
    const int total = NX4 + NW4;
    const int stride = 2048 * 256;
    for (int i = (bid - 768) * 256 + t; i < total; i += stride) {
        const float* s; unsigned short* d; int j;
        if (i < NX4) { s = x;  d = xb;  j = i; }
        else         { s = w2; d = w2b; j = i - NX4; }
        float4 v = *(const float4*)&s[(size_t)j * 4];
        ushort4 o;
        o.x = f2b(v.x); o.y = f2b(v.y); o.z = f2b(v.z); o.w = f2b(v.w);
        *(ushort4*)&d[(size_t)j * 4] = o;
    }
}

// ---------------------------------------------------------------------------
// fold: W1c[j,d] = sum_k Ucat[j,k] * wtT[d,k]  (pure bf16 GEMM, 2048x512x1024)
// ---------------------------------------------------------------------------
__global__ __launch_bounds__(256)
void fold_kernel(const unsigned short* __restrict__ A, const unsigned short* __restrict__ B,
                 unsigned short* __restrict__ C) {
    __shared__ unsigned short lds_a[BM * BK];
    __shared__ unsigned short lds_b[BN * BK];
    const int t = threadIdx.x;
    const int wave = t >> 6, lane = t & 63;
    const int wm = wave >> 1, wn = wave & 1;
    const int bm0 = blockIdx.y * BM;
    const int bn0 = blockIdx.x * BN;
    const int K = DIM, N = DMODEL;

    f32x4 acc[4][4] = {};
    const int c0 = t, c1 = t + 256;
    const int r0 = c0 >> 2, g0 = (c0 & 3) ^ ((r0 >> 1) & 3);
    const int r1 = c1 >> 2, g1 = (c1 & 3) ^ ((r1 >> 1) & 3);

    for (int k0 = 0; k0 < K; k0 += BK) {
        async_copy16(A + (size_t)(bm0 + r0) * K + k0 + g0 * 8, (char*)lds_a + wave * 1024);
        async_copy16(A + (size_t)(bm0 + r1) * K + k0 + g1 * 8, (char*)lds_a + wave * 1024 + 4096);
        async_copy16(B + (size_t)(bn0 + r0) * K + k0 + g0 * 8, (char*)lds_b + wave * 1024);
        async_copy16(B + (size_t)(bn0 + r1) * K + k0 + g1 * 8, (char*)lds_b + wave * 1024 + 4096);
        __syncthreads();

        bf16x8 af[4], bfr[4];
        #pragma unroll
        for (int i = 0; i < 4; i++) {
            int row = wm * 64 + i * 16 + (lane & 15);
            int slot = (lane >> 4) ^ ((row >> 1) & 3);
            af[i] = *(const bf16x8*)&lds_a[row * BK + slot * 8];
            int nrow = wn * 64 + i * 16 + (lane & 15);
            int nslot = (lane >> 4) ^ ((nrow >> 1) & 3);
            bfr[i] = *(const bf16x8*)&lds_b[nrow * BK + nslot * 8];
        }
        #pragma unroll
        for (int i = 0; i < 4; i++)
            #pragma unroll
            for (int j = 0; j < 4; j++)
                acc[i][j] = __builtin_amdgcn_mfma_f32_16x16x32_bf16(af[i], bfr[j], acc[i][j], 0, 0, 0);
        __syncthreads();
    }

    #pragma unroll
    for (int i = 0; i < 4; i++)
        #pragma unroll
        for (int j = 0; j < 4; j++) {
            int col = bn0 + wn * 64 + j * 16 + (lane & 15);
            #pragma unroll
            for (int r = 0; r < 4; r++) {
                int row = bm0 + wm * 64 + i * 16 + (lane >> 4) * 4 + r;
                C[(size_t)row * N + col] = f2b(acc[i][j][r]);
            }
        }
}

// ---------------------------------------------------------------------------
// gemm1: y = x_bf @ W1c^T + b2 (re/im interleaved cols). Epilogue: square,
// pair-sum, write p bf16 [TOKENS][DIM]. Grid: x=M (fast), y=N.
// ---------------------------------------------------------------------------
__global__ __launch_bounds__(256)
void gemm1_kernel(const unsigned short* __restrict__ A, const unsigned short* __restrict__ B,
                  const float* __restrict__ bias, unsigned short* __restrict__ P) {
    const int K = DMODEL;
    __shared__ unsigned short lds_a[BM * BK];
    __shared__ unsigned short lds_b[BN * BK];
    const int t = threadIdx.x;
    const int wave = t >> 6, lane = t & 63;
    const int wm = wave >> 1, wn = wave & 1;
    const int bm0 = blockIdx.x * BM;
    const int bn0 = blockIdx.y * BN;

    f32x4 acc[4][4] = {};
    const int c0 = t, c1 = t + 256;
    const int r0 = c0 >> 2, g0 = (c0 & 3) ^ ((r0 >> 1) & 3);
    const int r1 = c1 >> 2, g1 = (c1 & 3) ^ ((r1 >> 1) & 3);

    for (int k0 = 0; k0 < K; k0 += BK) {
        async_copy16(A + (size_t)(bm0 + r0) * K + k0 + g0 * 8, (char*)lds_a + wave * 1024);
        async_copy16(A + (size_t)(bm0 + r1) * K + k0 + g1 * 8, (char*)lds_a + wave * 1024 + 4096);
        async_copy16(B + (size_t)(bn0 + r0) * K + k0 + g0 * 8, (char*)lds_b + wave * 1024);
        async_copy16(B + (size_t)(bn0 + r1) * K + k0 + g1 * 8, (char*)lds_b + wave * 1024 + 4096);
        __syncthreads();

        bf16x8 af[4], bfr[4];
        #pragma unroll
        for (int i = 0; i < 4; i++) {
            int row = wm * 64 + i * 16 + (lane & 15);
            int slot = (lane >> 4) ^ ((row >> 1) & 3);
            af[i] = *(const bf16x8*)&lds_a[row * BK + slot * 8];
            int nrow = wn * 64 + i * 16 + (lane & 15);
            int nslot = (lane >> 4) ^ ((nrow >> 1) & 3);
            bfr[i] = *(const bf16x8*)&lds_b[nrow * BK + nslot * 8];
        }
        #pragma unroll
        for (int i = 0; i < 4; i++)
            #pragma unroll
            for (int j = 0; j < 4; j++)
                acc[i][j] = __builtin_amdgcn_mfma_f32_16x16x32_bf16(af[i], bfr[j], acc[i][j], 0, 0, 0);
        __syncthreads();
    }

    #pragma unroll
    for (int i = 0; i < 4; i++) {
        #pragma unroll
        for (int j = 0; j < 4; j++) {
            int col = bn0 + wn * 64 + j * 16 + (lane & 15);
            float bv = bias[col];
            #pragma unroll
            for (int r = 0; r < 4; r++) {
                int row = bm0 + wm * 64 + i * 16 + (lane >> 4) * 4 + r;
                float val = acc[i][j][r] + bv;
                float v2 = val * val;
                float v2p = v2 + __shfl_xor(v2, 1, 64);
                if (!(lane & 1))
                    P[(size_t)row * DIM + (col >> 1)] = f2b(v2p);
            }
        }
    }
}

// ---------------------------------------------------------------------------
// gemm2_ln: out = LN( (p@W_out^T)/n2 + b_out ) * ln_w + ln_b, where
// n2[row] = sum_k p[row,k] via all-ones B-fragment MFMA (wave 0 only).
// BM=32 x BN=512 (full d_model per block).
// ---------------------------------------------------------------------------
__global__ __launch_bounds__(256)
void gemm2_ln_kernel(const unsigned short* __restrict__ A,   // p [TOKENS][DIM]
                     const unsigned short* __restrict__ B,   // w2b [DMODEL][DIM]
                     const float* __restrict__ bias,
                     const float* __restrict__ lw, const float* __restrict__ lb,
                     float* __restrict__ out) {
    __shared__ unsigned short lds_a[32 * BK];
    __shared__ unsigned short lds_b[512 * BK];
    __shared__ float redS[4][32], redQ[4][32];
    __shared__ float muS[32], rsS[32], n2s[32];
    const int t = threadIdx.x, wave = t >> 6, lane = t & 63;
    const int bm0 = blockIdx.x * 32;

    f32x4 acc[2][8] = {};
    f32x4 accN[2] = {};
    bf16x8 ones;
    #pragma unroll
    for (int r = 0; r < 8; r++) ones[r] = (__bf16)1.0f;

    const int ra = t >> 2, ga = (t & 3) ^ ((ra >> 1) & 3);

    for (int k0 = 0; k0 < DIM; k0 += BK) {
        if (wave < 2)
            async_copy16(A + (size_t)(bm0 + ra) * DIM + k0 + ga * 8,
                         (char*)lds_a + wave * 1024);
        #pragma unroll
        for (int s = 0; s < 8; s++) {
            int c = t + s * 256;
            int r = c >> 2, g = (c & 3) ^ ((r >> 1) & 3);
            async_copy16(B + (size_t)r * DIM + k0 + g * 8,
                         (char*)lds_b + s * 4096 + wave * 1024);
        }
        __syncthreads();

        bf16x8 af[2], bfr[8];
        #pragma unroll
        for (int i = 0; i < 2; i++) {
            int row = i * 16 + (lane & 15);
            int slot = (lane >> 4) ^ ((row >> 1) & 3);
            af[i] = *(const bf16x8*)&lds_a[row * BK + slot * 8];
        }
        #pragma unroll
        for (int j = 0; j < 8; j++) {
            int nrow = wave * 128 + j * 16 + (lane & 15);
            int nslot = (lane >> 4) ^ ((nrow >> 1) & 3);
            bfr[j] = *(const bf16x8*)&lds_b[nrow * BK + nslot * 8];
        }
        #pragma unroll
        for (int i = 0; i < 2; i++)
            #pragma unroll
            for (int j = 0; j < 8; j++)
                acc[i][j] = __builtin_amdgcn_mfma_f32_16x16x32_bf16(af[i], bfr[j], acc[i][j], 0, 0, 0);
        if (wave == 0) {
            #pragma unroll
            for (int i = 0; i < 2; i++)
                accN[i] = __builtin_amdgcn_mfma_f32_16x16x32_bf16(af[i], ones, accN[i], 0, 0, 0);
        }
        __syncthreads();
    }

    if (wave == 0 && (lane & 15) == 0) {
        #pragma unroll
        for (int i = 0; i < 2; i++)
            #pragma unroll
            for (int r = 0; r < 4; r++)
                n2s[i * 16 + (lane >> 4) * 4 + r] = accN[i][r];
    }
    __syncthreads();

    const int colb = wave * 128;
    float nn[8];
    #pragma unroll
    for (int i = 0; i < 2; i++)
        #pragma unroll
        for (int r = 0; r < 4; r++) {
            int rl = i * 16 + (lane >> 4) * 4 + r;
            nn[i * 4 + r] = 1.0f / fmaxf(n2s[rl], 1e-24f);
        }
    float pS[8], pQ[8];
    #pragma unroll
    for (int i = 0; i < 2; i++)
        #pragma unroll
        for (int r = 0; r < 4; r++) {
            float s = 0.f, q = 0.f;
            #pragma unroll
            for (int j = 0; j < 8; j++) {
                int col = colb + j * 16 + (lane & 15);
                float val = acc[i][j][r] * nn[i * 4 + r] + bias[col];
                acc[i][j][r] = val;
                s += val; q += val * val;
            }
            s += __shfl_xor(s, 1, 64); q += __shfl_xor(q, 1, 64);
            s += __shfl_xor(s, 2, 64); q += __shfl_xor(q, 2, 64);
            s += __shfl_xor(s, 4, 64); q += __shfl_xor(q, 4, 64);
            s += __shfl_xor(s, 8, 64); q += __shfl_xor(q, 8, 64);
            pS[i * 4 + r] = s; pQ[i * 4 + r] = q;
        }
    if ((lane & 15) == 0) {
        #pragma unroll
        for (int i = 0; i < 2; i++)
            #pragma unroll
            for (int r = 0; r < 4; r++) {
                int rl = i * 16 + (lane >> 4) * 4 + r;
                redS[wave][rl] = pS[i * 4 + r];
                redQ[wave][rl] = pQ[i * 4 + r];
            }
    }
    __syncthreads();
    if (t < 32) {
        float s = redS[0][t] + redS[1][t] + redS[2][t] + redS[3][t];
        float q = redQ[0][t] + redQ[1][t] + redQ[2][t] + redQ[3][t];
        float mu = s * (1.0f / DMODEL);
        float var = q * (1.0f / DMODEL) - mu * mu;
        muS[t] = mu;
        rsS[t] = rsqrtf(var + 1e-5f);
    }
    __syncthreads();
    #pragma unroll
    for (int i = 0; i < 2; i++)
        #pragma unroll
        for (int j = 0; j < 8; j++) {
            int col = colb + j * 16 + (lane & 15);
            float w = lw[col], bb = lb[col];
            #pragma unroll
            for (int r = 0; r < 4; r++) {
                int rl = i * 16 + (lane >> 4) * 4 + r;
                out[(size_t)(bm0 + rl) * DMODEL + col] =
                    (acc[i][j][r] - muS[rl]) * rsS[rl] * w + bb;
            }
        }
}

extern "C" void kernel_launch(void* const* d_in, const int* in_sizes, int n_in,
                              void* d_out, int out_size, void* d_ws, size_t ws_size,
                              hipStream_t stream) {
    (void)in_sizes; (void)n_in; (void)out_size; (void)ws_size;
    const float* x     = (const float*)d_in[0];
    const float* W_in  = (const float*)d_in[1];
    const float* b_in  = (const float*)d_in[2];
    const float* W_out = (const float*)d_in[3];
    const float* b_out = (const float*)d_in[4];
    const float* rot   = (const float*)d_in[5];
    const float* ent   = (const float*)d_in[6];
    const float* ln_w  = (const float*)d_in[7];
    const float* ln_b  = (const float*)d_in[8];
    float* out = (float*)d_out;

    char* ws = (char*)d_ws;
    unsigned short* p    = (unsigned short*)ws;                     // [16384][1024] 32 MB
    unsigned short* x_bf = (unsigned short*)(ws + 33554432ull);     // 16 MB
    unsigned short* wtT  = (unsigned short*)(ws + 50331648ull);     // [512][1024] 1 MB
    unsigned short* w2b  = (unsigned short*)(ws + 51380224ull);     // [512][1024] 1 MB
    unsigned short* Ucat = (unsigned short*)(ws + 52428800ull);     // [2048][1024] 4 MB
    unsigned short* W1c  = (unsigned short*)(ws + 56623104ull);     // [2048][512] 2 MB
    float*          b2   = (float*)(ws + 58720256ull);              // [2048] 8 KB
    // high-water ~56 MB

    prep_all_kernel<<<2816, 256, 0, stream>>>(x, x_bf, W_out, w2b, W_in, wtT,
                                              rot, ent, b_in, Ucat, b2);
    fold_kernel<<<dim3(DMODEL / BN, 2 * DIM / BM), 256, 0, stream>>>(Ucat, wtT, W1c);
    gemm1_kernel<<<dim3(TOKENS / BM, 2 * DIM / BN), 256, 0, stream>>>(
        x_bf, W1c, b2, p);
    gemm2_ln_kernel<<<TOKENS / 32, 256, 0, stream>>>(
        p, w2b, b_out, ln_w, ln_b, out);
}